// Round 4
// baseline (334.504 us; speedup 1.0000x reference)
//
#include <hip/hip_runtime.h>
#include <hip/hip_bf16.h>

#define HIDDEN 512
#define IMGF   2048
#define RNDS   10

typedef float  f32x4  __attribute__((ext_vector_type(4)));
typedef __bf16 bf16x8 __attribute__((ext_vector_type(8)));
typedef unsigned short u16x8 __attribute__((ext_vector_type(8)));

__device__ __forceinline__ unsigned short f2bf(float x) {
    union { float f; unsigned u; } v; v.f = x;
    unsigned r = v.u + 0x7FFFu + ((v.u >> 16) & 1u);   // RNE
    return (unsigned short)(r >> 16);
}
__device__ __forceinline__ float bf2f(unsigned short h) {
    union { unsigned u; float f; } v; v.u = ((unsigned)h) << 16;
    return v.f;
}

__device__ __forceinline__ void cp16_async(const void* g, void* l) {
    __builtin_amdgcn_global_load_lds(
        (const __attribute__((address_space(1))) unsigned int*)g,
        (__attribute__((address_space(3))) unsigned int*)l,
        16, 0, 0);
}

// Pack 8 consecutive fp32 (two float4) -> bf16x8 fragment via v_cvt_pk_bf16_f32
__device__ __forceinline__ bf16x8 pack8(float4 p0, float4 p1) {
    union { bf16x8 v; __hip_bfloat162 h[4]; } u;
    u.h[0] = __float22bfloat162_rn(make_float2(p0.x, p0.y));
    u.h[1] = __float22bfloat162_rn(make_float2(p0.z, p0.w));
    u.h[2] = __float22bfloat162_rn(make_float2(p1.x, p1.y));
    u.h[3] = __float22bfloat162_rn(make_float2(p1.z, p1.w));
    return u.v;
}

// ---------------------------------------------------------------------------
// fp32 -> bf16 pre-convert, weights only (W_fuse + W_hist, 6.3 MB)
// ---------------------------------------------------------------------------
__global__ __launch_bounds__(256)
void cvt_bf16(const float* __restrict__ p0, long n0,
              const float* __restrict__ p1, long n1,
              unsigned short* __restrict__ q0, unsigned short* __restrict__ q1)
{
    long i = ((long)blockIdx.x * 256 + threadIdx.x) * 4;
    const float* s; unsigned short* d; long j;
    if (i < n0) { s = p0; d = q0; j = i; }
    else        { s = p1; d = q1; j = i - n0; }
    float4 v = *(const float4*)(s + j);
    ushort4 o;
    o.x = f2bf(v.x); o.y = f2bf(v.y); o.z = f2bf(v.z); o.w = f2bf(v.w);
    *(ushort4*)(d + j) = o;
}

// ---------------------------------------------------------------------------
// GEMM1: fusedb[m][n] = tanh( sum_k cat(img,ques)[m][k] * W[n][k] + bias[n] )
// A read DIRECTLY from fp32 global as register fragments (2x dwordx4 + cvt_pk
// per frag) -- no A-LDS, no pre-convert pass. B (bf16, L2-resident) staged
// via global_load_lds into XOR-swizzled LDS, double-buffered.
// Block = 128 threads = 2 waves, each wave a 32x64 tile; block tile 64x64.
// 1-D grid 640 with window swizzle: bx=(id/64)*8+id%8, by=(id/8)%8 ->
// one bm-group's 8 bn-blocks co-resident on ONE XCD -> A 8x L2 reuse.
// ---------------------------------------------------------------------------
__global__ __launch_bounds__(128, 4)
void gemm1(const float* __restrict__ A0,          // img  [.,2048] fp32
           const float* __restrict__ A1,          // ques [.,512]  fp32
           const unsigned short* __restrict__ W,  // W_fuse bf16 [512,2560]
           const float* __restrict__ bias,
           unsigned short* __restrict__ outb)     // fused bf16 [.,512]
{
    __shared__ unsigned short lB[2][64 * 64];
    const int id = blockIdx.x;
    const int bm = ((id >> 6) * 8 + (id & 7)) * 64;
    const int bn = ((id >> 3) & 7) * 64;
    const int t    = threadIdx.x;
    const int lane = t & 63;
    const int wv   = t >> 6;          // 0/1
    const int lr = lane & 15;
    const int lq = lane >> 4;
    const int K = IMGF + HIDDEN;      // 2560

    const unsigned short* Wb0 = W + (size_t)bn * K;
    auto stageB = [&](int kt, int buf) {
        int k0 = kt << 6;
        #pragma unroll
        for (int h = 0; h < 4; ++h) {       // 512 chunks / 128 threads
            int ci = h * 128 + t;
            int r = ci >> 3, s = (ci & 7) ^ (r & 7);
            cp16_async(Wb0 + k0 + (size_t)r * K + s * 8, &lB[buf][ci * 8]);
        }
    };

    // hoisted A row indices for this wave's two m-fragments
    const int row0 = bm + wv * 32 + lr;        // mi=0
    const int row1 = row0 + 16;                // mi=1

    f32x4 acc[2][4] = {};
    const int NT = K >> 6;                     // 40

    stageB(0, 0);
    for (int kt = 0; kt < NT; ++kt) {
        __syncthreads();                       // drain B tile kt
        if (kt + 1 < NT) stageB(kt + 1, (kt + 1) & 1);
        const unsigned short* b = &lB[kt & 1][0];
        const int k0 = kt << 6;
        // wave-uniform concat select (k-tile never crosses the 2048 boundary)
        const float* Ab; int lda, ko;
        if (k0 < IMGF) { Ab = A0; lda = IMGF;   ko = k0; }
        else           { Ab = A1; lda = HIDDEN; ko = k0 - IMGF; }
        #pragma unroll
        for (int kh = 0; kh < 2; ++kh) {
            const int kf = ko + kh * 32 + lq * 8;
            const float* r0p = Ab + (size_t)row0 * lda + kf;
            const float* r1p = Ab + (size_t)row1 * lda + kf;
            bf16x8 af[2];
            af[0] = pack8(*(const float4*)r0p, *(const float4*)(r0p + 4));
            af[1] = pack8(*(const float4*)r1p, *(const float4*)(r1p + 4));
            #pragma unroll
            for (int ni = 0; ni < 4; ++ni) {
                const int rb = ni * 16 + lr;
                const int c  = kh * 4 + lq;
                bf16x8 bfr = __builtin_bit_cast(bf16x8,
                    *(const u16x8*)&b[rb * 64 + ((c ^ (rb & 7)) * 8)]);
                #pragma unroll
                for (int mi = 0; mi < 2; ++mi)
                    acc[mi][ni] = __builtin_amdgcn_mfma_f32_16x16x32_bf16(
                        af[mi], bfr, acc[mi][ni], 0, 0, 0);
            }
        }
    }

    // epilogue: D[m = lq*4 + j][n = lr]  (verified m89/m91 layout)
    #pragma unroll
    for (int ni = 0; ni < 4; ++ni) {
        const int col = bn + ni * 16 + lr;
        const float bc = bias[col];
        #pragma unroll
        for (int mi = 0; mi < 2; ++mi) {
            const int rbase = bm + wv * 32 + mi * 16 + lq * 4;
            #pragma unroll
            for (int j = 0; j < 4; ++j)
                outb[(size_t)(rbase + j) * HIDDEN + col] =
                    f2bf(tanhf(acc[mi][ni][j] + bc));
        }
    }
}

// ---------------------------------------------------------------------------
// GEMM2: out[m][n] = fusedb[m][n] + tanh( sum_k hemb[m][k]*W_hist[n][k]+b[n] )
// A (hemb, bf16) read directly from global as 1x dwordx4 fragments.
// ---------------------------------------------------------------------------
__global__ __launch_bounds__(128, 4)
void gemm2(const unsigned short* __restrict__ A,  // hemb bf16 [.,512]
           const unsigned short* __restrict__ W,  // W_hist bf16 [512,512]
           const float* __restrict__ bias,
           const unsigned short* __restrict__ residb,
           float* __restrict__ outf)
{
    __shared__ unsigned short lB[2][64 * 64];
    const int id = blockIdx.x;
    const int bm = ((id >> 6) * 8 + (id & 7)) * 64;
    const int bn = ((id >> 3) & 7) * 64;
    const int t    = threadIdx.x;
    const int lane = t & 63;
    const int wv   = t >> 6;
    const int lr = lane & 15;
    const int lq = lane >> 4;
    const int K = HIDDEN;

    const unsigned short* Wb0 = W + (size_t)bn * K;
    auto stageB = [&](int kt, int buf) {
        int k0 = kt << 6;
        #pragma unroll
        for (int h = 0; h < 4; ++h) {
            int ci = h * 128 + t;
            int r = ci >> 3, s = (ci & 7) ^ (r & 7);
            cp16_async(Wb0 + k0 + (size_t)r * K + s * 8, &lB[buf][ci * 8]);
        }
    };

    const int row0 = bm + wv * 32 + lr;
    const int row1 = row0 + 16;

    f32x4 acc[2][4] = {};
    const int NT = K >> 6;                     // 8

    stageB(0, 0);
    for (int kt = 0; kt < NT; ++kt) {
        __syncthreads();
        if (kt + 1 < NT) stageB(kt + 1, (kt + 1) & 1);
        const unsigned short* b = &lB[kt & 1][0];
        const int k0 = kt << 6;
        #pragma unroll
        for (int kh = 0; kh < 2; ++kh) {
            const int kf = k0 + kh * 32 + lq * 8;
            bf16x8 af[2];
            af[0] = __builtin_bit_cast(bf16x8, *(const u16x8*)(A + (size_t)row0 * K + kf));
            af[1] = __builtin_bit_cast(bf16x8, *(const u16x8*)(A + (size_t)row1 * K + kf));
            #pragma unroll
            for (int ni = 0; ni < 4; ++ni) {
                const int rb = ni * 16 + lr;
                const int c  = kh * 4 + lq;
                bf16x8 bfr = __builtin_bit_cast(bf16x8,
                    *(const u16x8*)&b[rb * 64 + ((c ^ (rb & 7)) * 8)]);
                #pragma unroll
                for (int mi = 0; mi < 2; ++mi)
                    acc[mi][ni] = __builtin_amdgcn_mfma_f32_16x16x32_bf16(
                        af[mi], bfr, acc[mi][ni], 0, 0, 0);
            }
        }
    }

    #pragma unroll
    for (int ni = 0; ni < 4; ++ni) {
        const int col = bn + ni * 16 + lr;
        const float bc = bias[col];
        #pragma unroll
        for (int mi = 0; mi < 2; ++mi) {
            const int rbase = bm + wv * 32 + mi * 16 + lq * 4;
            #pragma unroll
            for (int j = 0; j < 4; ++j) {
                const size_t idx = (size_t)(rbase + j) * HIDDEN + col;
                outf[idx] = tanhf(acc[mi][ni][j] + bc) + bf2f(residb[idx]);
            }
        }
    }
}

// ---------------------------------------------------------------------------
// Attention: one wave per BR-row, lane holds 8 dims x 10 rounds in registers.
// No LDS, no barriers. fused is bf16; writes hist_embed as bf16 (GEMM2's A).
// ---------------------------------------------------------------------------
__global__ __launch_bounds__(256)
void attn_embed(const float* __restrict__ hist,
                const unsigned short* __restrict__ fusedb,
                const float* __restrict__ w_att,
                const float* __restrict__ b_att,
                unsigned short* __restrict__ hembed)
{
    const int lane = threadIdx.x & 63;
    const int wave = threadIdx.x >> 6;
    const int b = blockIdx.x * 4 + wave;
    const int d = lane * 8;

    float g[8];
    {
        u16x8 f = *(const u16x8*)(fusedb + (size_t)b * HIDDEN + d);
        const float4 w0 = *(const float4*)(w_att + d);
        const float4 w1 = *(const float4*)(w_att + d + 4);
        g[0]=bf2f(f[0])*w0.x; g[1]=bf2f(f[1])*w0.y; g[2]=bf2f(f[2])*w0.z; g[3]=bf2f(f[3])*w0.w;
        g[4]=bf2f(f[4])*w1.x; g[5]=bf2f(f[5])*w1.y; g[6]=bf2f(f[6])*w1.z; g[7]=bf2f(f[7])*w1.w;
    }
    const float* hb = hist + (size_t)b * RNDS * HIDDEN + d;

    float h[RNDS][8], p[RNDS];
    #pragma unroll
    for (int r = 0; r < RNDS; ++r) {
        const float4 a0 = *(const float4*)(hb + r * HIDDEN);
        const float4 a1 = *(const float4*)(hb + r * HIDDEN + 4);
        h[r][0]=a0.x; h[r][1]=a0.y; h[r][2]=a0.z; h[r][3]=a0.w;
        h[r][4]=a1.x; h[r][5]=a1.y; h[r][6]=a1.z; h[r][7]=a1.w;
        float s = 0.f;
        #pragma unroll
        for (int i = 0; i < 8; ++i) s += h[r][i] * g[i];
        p[r] = s;
    }
    #pragma unroll
    for (int r = 0; r < RNDS; ++r)
        #pragma unroll
        for (int m = 1; m < 64; m <<= 1)
            p[r] += __shfl_xor(p[r], m, 64);

    const float ba = b_att[0];
    float mx = -1e30f;
    #pragma unroll
    for (int r = 0; r < RNDS; ++r) mx = fmaxf(mx, p[r] + ba);
    float sum = 0.f, a[RNDS];
    #pragma unroll
    for (int r = 0; r < RNDS; ++r) { a[r] = __expf(p[r] + ba - mx); sum += a[r]; }
    const float inv = 1.0f / sum;

    float e[8] = {};
    #pragma unroll
    for (int r = 0; r < RNDS; ++r)
        #pragma unroll
        for (int i = 0; i < 8; ++i) e[i] += a[r] * h[r][i];

    ushort4 o0, o1;
    o0.x=f2bf(e[0]*inv); o0.y=f2bf(e[1]*inv); o0.z=f2bf(e[2]*inv); o0.w=f2bf(e[3]*inv);
    o1.x=f2bf(e[4]*inv); o1.y=f2bf(e[5]*inv); o1.z=f2bf(e[6]*inv); o1.w=f2bf(e[7]*inv);
    unsigned short* q = hembed + (size_t)b * HIDDEN + d;
    *(ushort4*)q = o0;
    *(ushort4*)(q + 4) = o1;
}

extern "C" void kernel_launch(void* const* d_in, const int* in_sizes, int n_in,
                              void* d_out, int out_size, void* d_ws, size_t ws_size,
                              hipStream_t stream)
{
    const float* img    = (const float*)d_in[0];
    const float* ques   = (const float*)d_in[1];
    const float* hist   = (const float*)d_in[2];
    const float* W_fuse = (const float*)d_in[3];
    const float* b_fuse = (const float*)d_in[4];
    const float* w_att  = (const float*)d_in[5];
    const float* b_att  = (const float*)d_in[6];
    const float* W_hist = (const float*)d_in[7];
    const float* b_hist = (const float*)d_in[8];

    const long n_Wf = in_sizes[3];               // 512*2560
    const long n_Wh = in_sizes[7];               // 512*512
    const int  BR   = in_sizes[1] / HIDDEN;      // 5120

    unsigned short* Wfb    = (unsigned short*)d_ws;
    unsigned short* Whb    = Wfb    + n_Wf;
    unsigned short* fusedb = Whb    + n_Wh;      // BR*512 bf16
    unsigned short* hembb  = fusedb + (size_t)BR * HIDDEN;

    // 1) weights fp32 -> bf16 (6.3 MB)
    const long total4 = (n_Wf + n_Wh) / 4;
    cvt_bf16<<<dim3((unsigned)((total4 + 255) / 256)), dim3(256), 0, stream>>>(
        W_fuse, n_Wf, W_hist, n_Wh, Wfb, Whb);

    const int nblk = (BR / 64) * (HIDDEN / 64);  // 640

    // 2) fusedb = tanh(cat(img,ques) @ W_fuse^T + b_fuse)   (bf16)
    gemm1<<<dim3(nblk), dim3(128), 0, stream>>>(
        img, ques, Wfb, b_fuse, fusedb);

    // 3) attention + weighted history sum -> hembb (bf16)
    attn_embed<<<dim3(BR / 4), dim3(256), 0, stream>>>(
        hist, fusedb, w_att, b_att, hembb);

    // 4) out = fusedb + tanh(hembb @ W_hist^T + b_hist)
    gemm2<<<dim3(nblk), dim3(128), 0, stream>>>(
        hembb, Whb, b_hist, fusedb, (float*)d_out);
}